// Round 1
// baseline (2664.432 us; speedup 1.0000x reference)
//
#include <hip/hip_runtime.h>
#include <hip/hip_bf16.h>

// Problem constants (from reference setup_inputs)
#define QN 100
#define BB 16
#define DD 256
#define TT 8192
#define DC 768
#define HH 8
#define HD 32

// attention split-T config
#define NS 8
#define TSL (TT / NS)   // 1024
#define TTILE 64
#define SSTR 68         // padded S stride (floats): 16B-aligned, bank-spread

// ---------------------------------------------------------------------------
// Kernel 1: q = (tgt + query_pos) @ Wq^T + bq, split heads, l2norm per head.
// Writes qn in [B, H, Q, hd] layout. Grid: Q*B blocks, 256 threads.
// ---------------------------------------------------------------------------
__global__ __launch_bounds__(256) void qproj_kernel(
    const float* __restrict__ tgt, const float* __restrict__ qpos,
    const float* __restrict__ Wq, const float* __restrict__ bq,
    float* __restrict__ qn_out) {
  int bid = blockIdx.x;           // q*B + b
  int q = bid >> 4, b = bid & 15;
  int e = threadIdx.x;            // 0..255
  __shared__ float arow[DD];
  size_t off = ((size_t)q * BB + b) * DD + e;
  arow[e] = tgt[off] + qpos[off];
  __syncthreads();
  const float4* w4 = (const float4*)(Wq + (size_t)e * DD);
  const float4* a4 = (const float4*)arow;
  float acc = bq[e];
#pragma unroll 8
  for (int i = 0; i < DD / 4; ++i) {
    float4 wv = w4[i], av = a4[i];
    acc += wv.x * av.x + wv.y * av.y + wv.z * av.z + wv.w * av.w;
  }
  // l2norm over each 32-wide head chunk (aligned 32-lane groups in the wave)
  float ss = acc * acc;
#pragma unroll
  for (int o = 16; o; o >>= 1) ss += __shfl_xor(ss, o, 64);
  float sc = 1.0f / fmaxf(sqrtf(ss), 1e-6f);
  qn_out[(((size_t)b * HH + (e >> 5)) * QN + q) * HD + (e & 31)] = acc * sc;
}

// ---------------------------------------------------------------------------
// Kernel 2: dual GEMM  K = text @ Wk^T + bk,  V = text @ Wv^T + bv.
// A = [M=B*T, 768], W = [256, 768] each. Outputs in [B,H,T,hd] layout
// (K un-normalized; l2norm folded into attention on the fly).
// BM=128, BN=128 (of N=512 concat), BK=16, 256 threads, 8x8 microtile.
// Grid 4096 blocks; XCD-chunked swizzle keeps the 4 N-tiles that share an
// A-panel consecutive within one XCD's dispatch chunk (A read ~once from HBM).
// ---------------------------------------------------------------------------
#define KV_BM 128
#define KV_BN 128
#define KV_BK 16
#define KV_PAD 132

__global__ __launch_bounds__(256) void kv_gemm_kernel(
    const float* __restrict__ text,
    const float* __restrict__ Wk, const float* __restrict__ bk,
    const float* __restrict__ Wv, const float* __restrict__ bv,
    float* __restrict__ Kout, float* __restrict__ Vout) {
  __shared__ float As[KV_BK][KV_PAD];
  __shared__ float Bs[KV_BK][KV_PAD];
  int bid = blockIdx.x;                       // 0..4095
  int w = (bid & 7) * 512 + (bid >> 3);       // XCD-contiguous chunks (4096%8==0)
  int mt = w >> 2;                            // 0..1023
  int nt = w & 3;                             // 0..3
  int m0 = mt * KV_BM;
  int n0 = nt * KV_BN;                        // 0,128 -> K ; 256,384 -> V
  int tid = threadIdx.x;
  int tm = tid & 15;                          // row group  (x8 rows)
  int tn = tid >> 4;                          // col group  (x8 cols)

  const float* Wbase = (n0 < 256) ? Wk : Wv;
  const float* bias_vec = (n0 < 256) ? bk : bv;
  float* dst = (n0 < 256) ? Kout : Vout;
  int ncol0 = n0 & 255;

  float acc[8][8];
#pragma unroll
  for (int i = 0; i < 8; ++i)
#pragma unroll
    for (int j = 0; j < 8; ++j) acc[i][j] = 0.0f;

  for (int k0 = 0; k0 < DC; k0 += KV_BK) {
#pragma unroll
    for (int c = 0; c < 2; ++c) {
      int idx = tid * 2 + c;                  // 0..511
      int r = idx >> 2;                       // 0..127
      int kc = (idx & 3) * 4;                 // 0,4,8,12
      float4 av = *(const float4*)(text + (size_t)(m0 + r) * DC + k0 + kc);
      As[kc + 0][r] = av.x; As[kc + 1][r] = av.y;
      As[kc + 2][r] = av.z; As[kc + 3][r] = av.w;
      float4 bw = *(const float4*)(Wbase + (size_t)(ncol0 + r) * DC + k0 + kc);
      Bs[kc + 0][r] = bw.x; Bs[kc + 1][r] = bw.y;
      Bs[kc + 2][r] = bw.z; Bs[kc + 3][r] = bw.w;
    }
    __syncthreads();
#pragma unroll
    for (int kk = 0; kk < KV_BK; ++kk) {
      float4 a0 = *(const float4*)&As[kk][tm * 8];
      float4 a1 = *(const float4*)&As[kk][tm * 8 + 4];
      float4 b0 = *(const float4*)&Bs[kk][tn * 8];
      float4 b1 = *(const float4*)&Bs[kk][tn * 8 + 4];
      float ar[8] = {a0.x, a0.y, a0.z, a0.w, a1.x, a1.y, a1.z, a1.w};
      float br[8] = {b0.x, b0.y, b0.z, b0.w, b1.x, b1.y, b1.z, b1.w};
#pragma unroll
      for (int i = 0; i < 8; ++i)
#pragma unroll
        for (int j = 0; j < 8; ++j)
          acc[i][j] = fmaf(ar[i], br[j], acc[i][j]);
    }
    __syncthreads();
  }
  // epilogue: bias + scatter to [B,H,T,hd]
#pragma unroll
  for (int j = 0; j < 8; ++j) {
    int e = ncol0 + tn * 8 + j;               // 0..255 within K or V
    float bias = bias_vec[e];
    int h = e >> 5, d = e & 31;
#pragma unroll
    for (int i = 0; i < 8; ++i) {
      int m = m0 + tm * 8 + i;
      int b = m >> 13;                        // / 8192
      int t = m & 8191;
      dst[(((size_t)(b * HH + h)) * TT + t) * HD + d] = acc[i][j] + bias;
    }
  }
}

// ---------------------------------------------------------------------------
// Kernel 3: attention partials. One block per (b, h, T-slice of 1024).
// No max-subtraction softmax (|logit| <= ~14.3 -> exp sums fit fp32 easily),
// so slices combine by plain addition downstream.
// Per 64-wide t-tile: phase A computes S=exp(logits) into LDS (k row in regs,
// l2norm of k on the fly, q rows broadcast from LDS); l-phase row-sums S;
// phase B accumulates PV into per-thread registers (8 qgroups x 32 d).
// ---------------------------------------------------------------------------
__global__ __launch_bounds__(256) void attn_partial_kernel(
    const float* __restrict__ qn, const float* __restrict__ Kraw,
    const float* __restrict__ Vb, const float* __restrict__ oov,
    const float* __restrict__ log_scale,
    float* __restrict__ part_acc, float* __restrict__ part_l) {
  __shared__ float S[QN * SSTR];      // 27.2 KB
  __shared__ float ql[QN * HD];       // 12.8 KB
  __shared__ float l_run[QN];
  int bid = blockIdx.x;
  int sl = bid & 7;                   // slice
  int bh = bid >> 3;                  // 0..127
  int b = bh >> 3;
  int h = bh & 7;
  int tid = threadIdx.x;

  float scale = fminf(expf(log_scale[0]), 100.0f);
  float alpha = (float)h * (1.0f / 7.0f);
  float cs = scale * (1.0f - alpha);

  // stage q rows for this (b,h)
  const float4* qsrc = (const float4*)(qn + (size_t)bh * QN * HD);
  for (int i = tid; i < QN * HD / 4; i += 256) ((float4*)ql)[i] = qsrc[i];
  if (tid < QN) l_run[tid] = 0.0f;
  __syncthreads();

  // phase B mapping
  int d = tid & 31, qg = tid >> 5;    // qg 0..7
  int nq = (qg < 4) ? 13 : 12;        // q = qg + 8j < 100
  float acc[13];
#pragma unroll
  for (int j = 0; j < 13; ++j) acc[j] = 0.0f;

  // phase A mapping
  int tt = tid & 63, qh = tid >> 6;   // qh 0..3 (25 q each); wave-uniform qh

  int t_base = sl * TSL;
  const float* orow = oov + (size_t)b * QN * TT;

  for (int tile = 0; tile < TSL; tile += TTILE) {
    int t0 = t_base + tile;
    {  // ---- phase A ----
      int t = t0 + tt;
      const float4* kp = (const float4*)(Kraw + ((size_t)bh * TT + t) * HD);
      float4 k0 = kp[0], k1 = kp[1], k2 = kp[2], k3 = kp[3];
      float4 k4 = kp[4], k5 = kp[5], k6 = kp[6], k7 = kp[7];
#define DOT4(a, b) ((a).x * (b).x + (a).y * (b).y + (a).z * (b).z + (a).w * (b).w)
      float ssq = DOT4(k0, k0) + DOT4(k1, k1) + DOT4(k2, k2) + DOT4(k3, k3) +
                  DOT4(k4, k4) + DOT4(k5, k5) + DOT4(k6, k6) + DOT4(k7, k7);
      float rk = 1.0f / fmaxf(sqrtf(ssq), 1e-6f);
      float csr = cs * rk;
#pragma unroll 2
      for (int j = 0; j < 25; ++j) {
        int q = qh * 25 + j;
        const float4* qp = (const float4*)&ql[q * HD];
        float4 q0 = qp[0], q1 = qp[1], q2 = qp[2], q3 = qp[3];
        float4 q4 = qp[4], q5 = qp[5], q6 = qp[6], q7 = qp[7];
        float dot = DOT4(q0, k0) + DOT4(q1, k1) + DOT4(q2, k2) + DOT4(q3, k3) +
                    DOT4(q4, k4) + DOT4(q5, k5) + DOT4(q6, k6) + DOT4(q7, k7);
        float lg = dot * csr + orow[(size_t)q * TT + t] * alpha;
        S[q * SSTR + tt] = __expf(lg);
      }
    }
    __syncthreads();
    // ---- l accumulation (threads 0..99 own one q row each) ----
    if (tid < QN) {
      float slsum = 0.0f;
#pragma unroll 4
      for (int t = 0; t < TTILE; ++t) slsum += S[tid * SSTR + t];
      l_run[tid] += slsum;
    }
    // ---- phase B: PV ----
    {
      const float* vcol = Vb + ((size_t)bh * TT + t0) * HD + d;
      for (int t4 = 0; t4 < TTILE; t4 += 4) {
        float v0 = vcol[(size_t)(t4 + 0) * HD];
        float v1 = vcol[(size_t)(t4 + 1) * HD];
        float v2 = vcol[(size_t)(t4 + 2) * HD];
        float v3 = vcol[(size_t)(t4 + 3) * HD];
        for (int j = 0; j < nq; ++j) {
          int q = qg + 8 * j;
          float4 p = *(const float4*)&S[q * SSTR + t4];
          acc[j] = fmaf(p.x, v0, acc[j]);
          acc[j] = fmaf(p.y, v1, acc[j]);
          acc[j] = fmaf(p.z, v2, acc[j]);
          acc[j] = fmaf(p.w, v3, acc[j]);
        }
      }
    }
    __syncthreads();
  }
  // write partials
  size_t pbase = ((size_t)bh * NS + sl) * QN;
  for (int j = 0; j < nq; ++j) {
    int q = qg + 8 * j;
    part_acc[(pbase + q) * HD + d] = acc[j];
  }
  if (tid < QN) part_l[pbase + tid] = l_run[tid];
}

// ---------------------------------------------------------------------------
// Kernel 4: combine partials -> attn row; out = row @ Wo^T + bo; residual+LN.
// Grid Q*B blocks, 256 threads (one output element each).
// ---------------------------------------------------------------------------
__global__ __launch_bounds__(256) void out_kernel(
    const float* __restrict__ part_acc, const float* __restrict__ part_l,
    const float* __restrict__ Wo, const float* __restrict__ bo,
    const float* __restrict__ tgt, const float* __restrict__ ln_g,
    const float* __restrict__ ln_b, float* __restrict__ out) {
  int bid = blockIdx.x;           // q*B + b
  int q = bid >> 4, b = bid & 15;
  int e = threadIdx.x;
  int h = e >> 5, d = e & 31;
  __shared__ float row[DD];
  __shared__ float r1[4], r2[4];

  size_t base = ((size_t)(b * HH + h)) * NS * QN + q;
  float a = 0.0f, lt = 0.0f;
#pragma unroll
  for (int s = 0; s < NS; ++s) {
    a += part_acc[(base + (size_t)s * QN) * HD + d];
    lt += part_l[base + (size_t)s * QN];
  }
  row[e] = a / lt;
  __syncthreads();

  const float4* w4 = (const float4*)(Wo + (size_t)e * DD);
  const float4* r4 = (const float4*)row;
  float o = bo[e];
#pragma unroll 8
  for (int i = 0; i < DD / 4; ++i) {
    float4 wv = w4[i], rv = r4[i];
    o += wv.x * rv.x + wv.y * rv.y + wv.z * rv.z + wv.w * rv.w;
  }
  float x = tgt[((size_t)q * BB + b) * DD + e] + o;

  float s1 = x, s2 = x * x;
#pragma unroll
  for (int off = 32; off; off >>= 1) {
    s1 += __shfl_xor(s1, off, 64);
    s2 += __shfl_xor(s2, off, 64);
  }
  int wid = e >> 6, lane = e & 63;
  if (lane == 0) { r1[wid] = s1; r2[wid] = s2; }
  __syncthreads();
  float T1 = r1[0] + r1[1] + r1[2] + r1[3];
  float T2 = r2[0] + r2[1] + r2[2] + r2[3];
  float mu = T1 * (1.0f / DD);
  float var = T2 * (1.0f / DD) - mu * mu;
  out[((size_t)q * BB + b) * DD + e] =
      (x - mu) * rsqrtf(var + 1e-5f) * ln_g[e] + ln_b[e];
}

// ---------------------------------------------------------------------------
extern "C" void kernel_launch(void* const* d_in, const int* in_sizes, int n_in,
                              void* d_out, int out_size, void* d_ws, size_t ws_size,
                              hipStream_t stream) {
  (void)in_sizes; (void)n_in; (void)out_size; (void)ws_size;
  const float* tgt  = (const float*)d_in[0];
  const float* text = (const float*)d_in[1];
  const float* qpos = (const float*)d_in[2];
  const float* oov  = (const float*)d_in[3];
  const float* Wq = (const float*)d_in[4];
  const float* bq = (const float*)d_in[5];
  const float* Wk = (const float*)d_in[6];
  const float* bk = (const float*)d_in[7];
  const float* Wv = (const float*)d_in[8];
  const float* bv = (const float*)d_in[9];
  const float* Wo = (const float*)d_in[10];
  const float* bo = (const float*)d_in[11];
  const float* ln_g = (const float*)d_in[12];
  const float* ln_b = (const float*)d_in[13];
  const float* log_scale = (const float*)d_in[14];
  float* out = (float*)d_out;

  // workspace layout (floats); total 70,897,664 floats = 283.6 MB
  float* ws = (float*)d_ws;
  float* qn_ws = ws;                                        //   409,600
  float* Kraw  = qn_ws + (size_t)BB * HH * QN * HD;         //  33,554,432
  float* Vb    = Kraw  + (size_t)BB * HH * TT * HD;         //  33,554,432
  float* pacc  = Vb    + (size_t)BB * HH * TT * HD;         //   3,276,800
  float* pl    = pacc  + (size_t)BB * HH * NS * QN * HD;    //     102,400

  hipLaunchKernelGGL(qproj_kernel, dim3(QN * BB), dim3(DD), 0, stream,
                     tgt, qpos, Wq, bq, qn_ws);
  hipLaunchKernelGGL(kv_gemm_kernel, dim3(4096), dim3(256), 0, stream,
                     text, Wk, bk, Wv, bv, Kraw, Vb);
  hipLaunchKernelGGL(attn_partial_kernel, dim3(BB * HH * NS), dim3(256), 0, stream,
                     qn_ws, Kraw, Vb, oov, log_scale, pacc, pl);
  hipLaunchKernelGGL(out_kernel, dim3(QN * BB), dim3(DD), 0, stream,
                     pacc, pl, Wo, bo, tgt, ln_g, ln_b, out);
}

// Round 3
// 1551.574 us; speedup vs baseline: 1.7172x; 1.7172x over previous
//
#include <hip/hip_runtime.h>
#include <hip/hip_bf16.h>

// Problem constants
#define QN 100
#define QP 112            // padded Q rows (7 x 16)
#define BB 16
#define DD 256
#define TT 8192
#define DC 768
#define HH 8
#define HD 32
#define NS 8              // T slices
#define TSL (TT / NS)     // 1024

typedef short bf16x4 __attribute__((ext_vector_type(4)));
typedef short bf16x8 __attribute__((ext_vector_type(8)));
typedef float f32x4 __attribute__((ext_vector_type(4)));

__device__ __forceinline__ uint pack_bf16_hi2(float f0, float f1) {
  return (__float_as_uint(f0) >> 16) | (__float_as_uint(f1) & 0xffff0000u);
}

// ---------------------------------------------------------------------------
// Kernel 1: q = (tgt+query_pos)@Wq^T + bq, head-split, l2norm, bf16 hi/lo
// planes [bh][112][32] (rows 100..111 zero). Grid 112*16 blocks x 256.
// ---------------------------------------------------------------------------
__global__ __launch_bounds__(256) void qproj_kernel(
    const float* __restrict__ tgt, const float* __restrict__ qpos,
    const float* __restrict__ Wq, const float* __restrict__ bq,
    ushort* __restrict__ Qhi, ushort* __restrict__ Qlo) {
  int bid = blockIdx.x;           // q*16 + b
  int q = bid >> 4, b = bid & 15;
  int e = threadIdx.x;            // 0..255
  int h = e >> 5, d = e & 31;
  size_t widx = ((size_t)(b * HH + h) * QP + q) * HD + d;
  if (q >= QN) { Qhi[widx] = 0; Qlo[widx] = 0; return; }
  __shared__ float arow[DD];
  size_t off = ((size_t)q * BB + b) * DD + e;
  arow[e] = tgt[off] + qpos[off];
  __syncthreads();
  const float4* w4 = (const float4*)(Wq + (size_t)e * DD);
  const float4* a4 = (const float4*)arow;
  float acc = bq[e];
#pragma unroll 8
  for (int i = 0; i < DD / 4; ++i) {
    float4 wv = w4[i], av = a4[i];
    acc += wv.x * av.x + wv.y * av.y + wv.z * av.z + wv.w * av.w;
  }
  float ss = acc * acc;
#pragma unroll
  for (int o = 16; o; o >>= 1) ss += __shfl_xor(ss, o, 64);
  float qn = acc * (1.0f / fmaxf(sqrtf(ss), 1e-6f));
  uint u = __float_as_uint(qn);
  float hif = __uint_as_float(u & 0xffff0000u);
  Qhi[widx] = (ushort)(u >> 16);
  Qlo[widx] = (ushort)(__float_as_uint(qn - hif) >> 16);
}

// ---------------------------------------------------------------------------
// Kernel 2: dual GEMM K = text@Wk^T+bk, V = text@Wv^T+bv via bf16x3-split
// MFMA. BM=128,BN=128(concat 512),BK=32, 4 waves 2x2, 4x4 16x16x32 frags.
// Writes fp32 K/V in [bh][t][d]. (unchanged from round 2)
// ---------------------------------------------------------------------------
__global__ __launch_bounds__(256) void kv_gemm_kernel(
    const float* __restrict__ text,
    const float* __restrict__ Wk, const float* __restrict__ bk,
    const float* __restrict__ Wv, const float* __restrict__ bv,
    float* __restrict__ Kout, float* __restrict__ Vout) {
  __shared__ short Ahi[4][129][8];
  __shared__ short Alo[4][129][8];
  __shared__ short Bhi[4][129][8];
  __shared__ short Blo[4][129][8];

  int bid = blockIdx.x;                       // 0..4095
  int w = (bid & 7) * 512 + (bid >> 3);       // XCD-contiguous chunks
  int mt = w >> 2, nt = w & 3;
  int m0 = mt * 128, n0 = nt * 128;
  int tid = threadIdx.x;

  const float* Wbase = (n0 < 256) ? Wk : Wv;
  const float* bias_vec = (n0 < 256) ? bk : bv;
  float* dst = (n0 < 256) ? Kout : Vout;
  int ncol0 = n0 & 255;

  int r = tid & 127;
  bool isA = tid < 128;
  const float* src = isA ? (text + (size_t)(m0 + r) * DC)
                         : (Wbase + (size_t)(ncol0 + r) * DC);
  short (*dhi)[129][8] = isA ? Ahi : Bhi;
  short (*dlo)[129][8] = isA ? Alo : Blo;

  int lane = tid & 63, wid = tid >> 6;
  int wm = wid >> 1, wn = wid & 1;
  int kg = lane >> 4, fr = lane & 15;

  f32x4 acc[4][4];
#pragma unroll
  for (int i = 0; i < 4; ++i)
#pragma unroll
    for (int j = 0; j < 4; ++j) acc[i][j] = (f32x4){0.f, 0.f, 0.f, 0.f};

  float4 ra[8];
#pragma unroll
  for (int c = 0; c < 8; ++c) ra[c] = *(const float4*)(src + c * 4);

  for (int ks = 0; ks < DC / 32; ++ks) {
    const float* raf = (const float*)ra;
#pragma unroll
    for (int g = 0; g < 4; ++g) {
      uint hiw[4], low[4];
#pragma unroll
      for (int p = 0; p < 4; ++p) {
        float f0 = raf[8 * g + 2 * p], f1 = raf[8 * g + 2 * p + 1];
        uint b0 = __float_as_uint(f0), b1 = __float_as_uint(f1);
        float h0 = __uint_as_float(b0 & 0xffff0000u);
        float h1 = __uint_as_float(b1 & 0xffff0000u);
        hiw[p] = (b0 >> 16) | (b1 & 0xffff0000u);
        low[p] = (__float_as_uint(f0 - h0) >> 16) |
                 (__float_as_uint(f1 - h1) & 0xffff0000u);
      }
      *(uint4*)&dhi[g][r][0] = make_uint4(hiw[0], hiw[1], hiw[2], hiw[3]);
      *(uint4*)&dlo[g][r][0] = make_uint4(low[0], low[1], low[2], low[3]);
    }
    __syncthreads();

    if (ks < DC / 32 - 1) {
      const float* s2 = src + (ks + 1) * 32;
#pragma unroll
      for (int c = 0; c < 8; ++c) ra[c] = *(const float4*)(s2 + c * 4);
    }

    bf16x8 bh[4], bl[4];
#pragma unroll
    for (int ni = 0; ni < 4; ++ni) {
      int row = wn * 64 + ni * 16 + fr;
      bh[ni] = *(const bf16x8*)&Bhi[kg][row][0];
      bl[ni] = *(const bf16x8*)&Blo[kg][row][0];
    }
#pragma unroll
    for (int mi = 0; mi < 4; ++mi) {
      int row = wm * 64 + mi * 16 + fr;
      bf16x8 ah = *(const bf16x8*)&Ahi[kg][row][0];
      bf16x8 al = *(const bf16x8*)&Alo[kg][row][0];
#pragma unroll
      for (int ni = 0; ni < 4; ++ni) {
        acc[mi][ni] = __builtin_amdgcn_mfma_f32_16x16x32_bf16(
            ah, bh[ni], acc[mi][ni], 0, 0, 0);
        acc[mi][ni] = __builtin_amdgcn_mfma_f32_16x16x32_bf16(
            ah, bl[ni], acc[mi][ni], 0, 0, 0);
        acc[mi][ni] = __builtin_amdgcn_mfma_f32_16x16x32_bf16(
            al, bh[ni], acc[mi][ni], 0, 0, 0);
      }
    }
    __syncthreads();
  }

#pragma unroll
  for (int ni = 0; ni < 4; ++ni) {
    int col = n0 + wn * 64 + ni * 16 + fr;
    int e = col & 255;
    int h = e >> 5, d = e & 31;
    float bias = bias_vec[e];
#pragma unroll
    for (int mi = 0; mi < 4; ++mi) {
      f32x4 c = acc[mi][ni];
      int mbase = m0 + wm * 64 + mi * 16 + kg * 4;
#pragma unroll
      for (int j = 0; j < 4; ++j) {
        int m = mbase + j;
        int b = m >> 13, t = m & 8191;
        dst[(((size_t)(b * HH + h)) * TT + t) * HD + d] = c[j] + bias;
      }
    }
  }
}

// ---------------------------------------------------------------------------
// Kernel 2.5: prep — convert K/V fp32 -> bf16 hi/lo planes IN PLACE,
// chunk-local (chunk = 256 t rows = 32KB). K: l2norm folded, layout
// [2][256][32] shorts. V: transposed to [2][32][256] shorts.
// Grid 4096 blocks (bh*32 + tc) x 256 threads.
// ---------------------------------------------------------------------------
__global__ __launch_bounds__(256) void prep_kernel(float* __restrict__ Kbuf,
                                                   float* __restrict__ Vbuf) {
  __shared__ float vl[32][257];   // [d][t] padded
  int c = blockIdx.x;
  int tid = threadIdx.x;
  float* Kc = Kbuf + (size_t)c * 8192;
  float* Vc = Vbuf + (size_t)c * 8192;

  // read own K row (t = tid) into regs
  float kr[32];
#pragma unroll
  for (int i = 0; i < 8; ++i)
    *(float4*)&kr[i * 4] = *(const float4*)(Kc + (size_t)tid * 32 + i * 4);
  // read own V row, scatter into LDS transpose buffer
#pragma unroll
  for (int i = 0; i < 8; ++i) {
    float4 v = *(const float4*)(Vc + (size_t)tid * 32 + i * 4);
    vl[i * 4 + 0][tid] = v.x;
    vl[i * 4 + 1][tid] = v.y;
    vl[i * 4 + 2][tid] = v.z;
    vl[i * 4 + 3][tid] = v.w;
  }
  __syncthreads();   // all fp32 reads complete before any in-place writes

  // K: normalize + split + write in place
  float ss = 0.f;
#pragma unroll
  for (int i = 0; i < 32; ++i) ss += kr[i] * kr[i];
  float rk = 1.0f / fmaxf(sqrtf(ss), 1e-6f);
  ushort* Kh = (ushort*)Kc;       // [2][256][32] shorts
  uint hiw[16], low[16];
#pragma unroll
  for (int p = 0; p < 16; ++p) {
    float f0 = kr[2 * p] * rk, f1 = kr[2 * p + 1] * rk;
    uint b0 = __float_as_uint(f0), b1 = __float_as_uint(f1);
    float h0 = __uint_as_float(b0 & 0xffff0000u);
    float h1 = __uint_as_float(b1 & 0xffff0000u);
    hiw[p] = (b0 >> 16) | (b1 & 0xffff0000u);
    low[p] = (__float_as_uint(f0 - h0) >> 16) |
             (__float_as_uint(f1 - h1) & 0xffff0000u);
  }
#pragma unroll
  for (int i = 0; i < 4; ++i) {
    *(uint4*)(Kh + (size_t)tid * 32 + i * 8) =
        make_uint4(hiw[4 * i], hiw[4 * i + 1], hiw[4 * i + 2], hiw[4 * i + 3]);
    *(uint4*)(Kh + 8192 + (size_t)tid * 32 + i * 8) =
        make_uint4(low[4 * i], low[4 * i + 1], low[4 * i + 2], low[4 * i + 3]);
  }

  // V: read column strip from LDS, split, write transposed in place
  int d = tid & 31, c8 = tid >> 5;   // lanes 0..31 = consecutive d
  float vv[32];
#pragma unroll
  for (int t = 0; t < 32; ++t) vv[t] = vl[d][c8 * 32 + t];
  ushort* Vh = (ushort*)Vc;          // [2][32][256] shorts
#pragma unroll
  for (int p = 0; p < 16; ++p) {
    float f0 = vv[2 * p], f1 = vv[2 * p + 1];
    uint b0 = __float_as_uint(f0), b1 = __float_as_uint(f1);
    float h0 = __uint_as_float(b0 & 0xffff0000u);
    float h1 = __uint_as_float(b1 & 0xffff0000u);
    hiw[p] = (b0 >> 16) | (b1 & 0xffff0000u);
    low[p] = (__float_as_uint(f0 - h0) >> 16) |
             (__float_as_uint(f1 - h1) & 0xffff0000u);
  }
#pragma unroll
  for (int i = 0; i < 4; ++i) {
    *(uint4*)(Vh + (size_t)d * 256 + c8 * 32 + i * 8) =
        make_uint4(hiw[4 * i], hiw[4 * i + 1], hiw[4 * i + 2], hiw[4 * i + 3]);
    *(uint4*)(Vh + 8192 + (size_t)d * 256 + c8 * 32 + i * 8) =
        make_uint4(low[4 * i], low[4 * i + 1], low[4 * i + 2], low[4 * i + 3]);
  }
}

// ---------------------------------------------------------------------------
// Kernel 3: MFMA attention partials. Block = (bh, slice). 4 waves, each owns
// a 32-t window per 128-t step; barrier-free t-loop. QK^T: 3 mfma hi/lo;
// P split hi/lo into per-wave LDS tile; PV: 3 mfma. fp32 row-sums in regs.
// ---------------------------------------------------------------------------
__global__ __launch_bounds__(256, 2) void attn_kernel(
    const ushort* __restrict__ Qhi, const ushort* __restrict__ Qlo,
    const ushort* __restrict__ Kpl, const ushort* __restrict__ Vpl,
    const float* __restrict__ oov, const float* __restrict__ log_scale,
    float* __restrict__ pacc, float* __restrict__ pl) {
  __shared__ short Pbuf[4][2][QP][36];   // per-wave P hi/lo tiles, 63 KB
  int bid = blockIdx.x;
  int sl = bid & 7, bh = bid >> 3;
  int b = bh >> 3, h = bh & 7;
  int tid = threadIdx.x, lane = tid & 63, w = tid >> 6;
  int fr = lane & 15, kg = lane >> 4;

  float scale = fminf(__expf(log_scale[0]), 100.0f);
  float alpha = (float)h * (1.0f / 7.0f);
  float cs = scale * (1.0f - alpha);

  // Q fragments (persistent)
  bf16x8 qhf[7], qlf[7];
#pragma unroll
  for (int qt = 0; qt < 7; ++qt) {
    size_t qa = ((size_t)bh * QP + qt * 16 + fr) * HD + kg * 8;
    qhf[qt] = *(const bf16x8*)(Qhi + qa);
    qlf[qt] = *(const bf16x8*)(Qlo + qa);
  }

  f32x4 oacc[7][2];
#pragma unroll
  for (int qt = 0; qt < 7; ++qt)
#pragma unroll
    for (int dt = 0; dt < 2; ++dt) oacc[qt][dt] = (f32x4){0.f, 0.f, 0.f, 0.f};
  float lsum[7][4];
#pragma unroll
  for (int qt = 0; qt < 7; ++qt)
#pragma unroll
    for (int j = 0; j < 4; ++j) lsum[qt][j] = 0.f;

  short* Ph = &Pbuf[w][0][0][0];
  short* Pl = &Pbuf[w][1][0][0];
  const float* oovb = oov + (size_t)b * QN * TT;

  for (int s = 0; s < 8; ++s) {
    int t0 = sl * TSL + s * 128 + w * 32;
    int c = bh * 32 + (t0 >> 8);
    int ttb = t0 & 255;
    const ushort* Kc = Kpl + (size_t)c * 16384;
    const ushort* Vc = Vpl + (size_t)c * 16384;

    // K fragments for the two 16-t tiles
    bf16x8 kh[2], kl[2];
#pragma unroll
    for (int tt = 0; tt < 2; ++tt) {
      int off = (ttb + tt * 16 + fr) * HD + kg * 8;
      kh[tt] = *(const bf16x8*)(Kc + off);
      kl[tt] = *(const bf16x8*)(Kc + 8192 + off);
    }

    // QK^T + exp + split into LDS
#pragma unroll
    for (int qt = 0; qt < 7; ++qt) {
#pragma unroll
      for (int tt = 0; tt < 2; ++tt) {
        f32x4 sacc = (f32x4){0.f, 0.f, 0.f, 0.f};
        sacc = __builtin_amdgcn_mfma_f32_16x16x32_bf16(qhf[qt], kh[tt], sacc, 0, 0, 0);
        sacc = __builtin_amdgcn_mfma_f32_16x16x32_bf16(qlf[qt], kh[tt], sacc, 0, 0, 0);
        sacc = __builtin_amdgcn_mfma_f32_16x16x32_bf16(qhf[qt], kl[tt], sacc, 0, 0, 0);
        int tcol = t0 + tt * 16 + fr;
#pragma unroll
        for (int j = 0; j < 4; ++j) {
          int q = qt * 16 + kg * 4 + j;
          int qc = q < QN ? q : QN - 1;
          float ov = oovb[(size_t)qc * TT + tcol];
          float S = __expf(sacc[j] * cs + ov * alpha);
          lsum[qt][j] += S;
          uint u = __float_as_uint(S);
          float hif = __uint_as_float(u & 0xffff0000u);
          Ph[q * 36 + tt * 16 + fr] = (short)(u >> 16);
          Pl[q * 36 + tt * 16 + fr] = (short)(__float_as_uint(S - hif) >> 16);
        }
      }
    }

    // V fragments
    bf16x8 vh[2], vlo[2];
#pragma unroll
    for (int dt = 0; dt < 2; ++dt) {
      int off = (dt * 16 + fr) * 256 + ttb + kg * 8;
      vh[dt] = *(const bf16x8*)(Vc + off);
      vlo[dt] = *(const bf16x8*)(Vc + 8192 + off);
    }

    // PV
#pragma unroll
    for (int qt = 0; qt < 7; ++qt) {
      int qrow = qt * 16 + fr;
      bf16x4 ph0 = *(const bf16x4*)&Ph[qrow * 36 + kg * 8];
      bf16x4 ph1 = *(const bf16x4*)&Ph[qrow * 36 + kg * 8 + 4];
      bf16x4 pl0 = *(const bf16x4*)&Pl[qrow * 36 + kg * 8];
      bf16x4 pl1 = *(const bf16x4*)&Pl[qrow * 36 + kg * 8 + 4];
      bf16x8 pా = __builtin_shufflevector(ph0, ph1, 0, 1, 2, 3, 4, 5, 6, 7);
      bf16x8 plv = __builtin_shufflevector(pl0, pl1, 0, 1, 2, 3, 4, 5, 6, 7);
#pragma unroll
      for (int dt = 0; dt < 2; ++dt) {
        oacc[qt][dt] = __builtin_amdgcn_mfma_f32_16x16x32_bf16(pా, vh[dt], oacc[qt][dt], 0, 0, 0);
        oacc[qt][dt] = __builtin_amdgcn_mfma_f32_16x16x32_bf16(plv, vh[dt], oacc[qt][dt], 0, 0, 0);
        oacc[qt][dt] = __builtin_amdgcn_mfma_f32_16x16x32_bf16(pా, vlo[dt], oacc[qt][dt], 0, 0, 0);
      }
    }
  }

  // reduce l across the 16 fr lanes of each quarter
#pragma unroll
  for (int qt = 0; qt < 7; ++qt)
#pragma unroll
    for (int j = 0; j < 4; ++j) {
      float v = lsum[qt][j];
      v += __shfl_xor(v, 1, 64);
      v += __shfl_xor(v, 2, 64);
      v += __shfl_xor(v, 4, 64);
      v += __shfl_xor(v, 8, 64);
      lsum[qt][j] = v;
    }

  // dump per-wave partial out + l into own LDS region (P tile is dead)
  float* red = (float*)&Pbuf[w][0][0][0];   // 4032 floats available
#pragma unroll
  for (int qt = 0; qt < 7; ++qt)
#pragma unroll
    for (int dt = 0; dt < 2; ++dt)
#pragma unroll
      for (int j = 0; j < 4; ++j)
        red[(qt * 16 + kg * 4 + j) * HD + dt * 16 + fr] = oacc[qt][dt][j];
  if (fr == 0) {
#pragma unroll
    for (int qt = 0; qt < 7; ++qt)
#pragma unroll
      for (int j = 0; j < 4; ++j)
        red[QP * HD + qt * 16 + kg * 4 + j] = lsum[qt][j];
  }
  __syncthreads();

  // cross-wave sum + write partials
  const int WSTRIDE = 2 * QP * 36 / 2;   // floats per wave region = 4032
  float* r0 = (float*)&Pbuf[0][0][0][0];
  size_t pbase = ((size_t)bh * NS + sl) * QN;
  for (int idx = tid; idx < QN * HD; idx += 256) {
    int q = idx >> 5, d = idx & 31;
    float ssum = 0.f;
#pragma unroll
    for (int wv = 0; wv < 4; ++wv) ssum += r0[wv * WSTRIDE + (q * HD + d)];
    pacc[(pbase + q) * HD + d] = ssum;
  }
  if (tid < QN) {
    float lt = 0.f;
#pragma unroll
    for (int wv = 0; wv < 4; ++wv) lt += r0[wv * WSTRIDE + QP * HD + tid];
    pl[pbase + tid] = lt;
  }
}

// ---------------------------------------------------------------------------
// Kernel 4: combine partials -> attn row; out = row@Wo^T + bo; residual+LN.
// ---------------------------------------------------------------------------
__global__ __launch_bounds__(256) void out_kernel(
    const float* __restrict__ part_acc, const float* __restrict__ part_l,
    const float* __restrict__ Wo, const float* __restrict__ bo,
    const float* __restrict__ tgt, const float* __restrict__ ln_g,
    const float* __restrict__ ln_b, float* __restrict__ out) {
  int bid = blockIdx.x;           // q*B + b
  int q = bid >> 4, b = bid & 15;
  int e = threadIdx.x;
  int h = e >> 5, d = e & 31;
  __shared__ float row[DD];
  __shared__ float r1[4], r2[4];

  size_t base = ((size_t)(b * HH + h)) * NS * QN + q;
  float a = 0.0f, lt = 0.0f;
#pragma unroll
  for (int s = 0; s < NS; ++s) {
    a += part_acc[(base + (size_t)s * QN) * HD + d];
    lt += part_l[base + (size_t)s * QN];
  }
  row[e] = a / lt;
  __syncthreads();

  const float4* w4 = (const float4*)(Wo + (size_t)e * DD);
  const float4* r4 = (const float4*)row;
  float o = bo[e];
#pragma unroll 8
  for (int i = 0; i < DD / 4; ++i) {
    float4 wv = w4[i], rv = r4[i];
    o += wv.x * rv.x + wv.y * rv.y + wv.z * rv.z + wv.w * rv.w;
  }
  float x = tgt[((size_t)q * BB + b) * DD + e] + o;

  float s1 = x, s2 = x * x;
#pragma unroll
  for (int off = 32; off; off >>= 1) {
    s1 += __shfl_xor(s1, off, 64);
    s2 += __shfl_xor(s2, off, 64);
  }
  int wid = e >> 6, lane = e & 63;
  if (lane == 0) { r1[wid] = s1; r2[wid] = s2; }
  __syncthreads();
  float T1 = r1[0] + r1[1] + r1[2] + r1[3];
  float T2 = r2[0] + r2[1] + r2[2] + r2[3];
  float mu = T1 * (1.0f / DD);
  float var = T2 * (1.0f / DD) - mu * mu;
  out[((size_t)q * BB + b) * DD + e] =
      (x - mu) * rsqrtf(var + 1e-5f) * ln_g[e] + ln_b[e];
}

// ---------------------------------------------------------------------------
extern "C" void kernel_launch(void* const* d_in, const int* in_sizes, int n_in,
                              void* d_out, int out_size, void* d_ws, size_t ws_size,
                              hipStream_t stream) {
  (void)in_sizes; (void)n_in; (void)out_size; (void)ws_size;
  const float* tgt  = (const float*)d_in[0];
  const float* text = (const float*)d_in[1];
  const float* qpos = (const float*)d_in[2];
  const float* oov  = (const float*)d_in[3];
  const float* Wq = (const float*)d_in[4];
  const float* bq = (const float*)d_in[5];
  const float* Wk = (const float*)d_in[6];
  const float* bk = (const float*)d_in[7];
  const float* Wv = (const float*)d_in[8];
  const float* bv = (const float*)d_in[9];
  const float* Wo = (const float*)d_in[10];
  const float* bo = (const float*)d_in[11];
  const float* ln_g = (const float*)d_in[12];
  const float* ln_b = (const float*)d_in[13];
  const float* log_scale = (const float*)d_in[14];
  float* out = (float*)d_out;

  // workspace layout (~284 MB)
  char* wsb = (char*)d_ws;
  ushort* Qhi = (ushort*)wsb;                       //   917,504 B
  ushort* Qlo = Qhi + (size_t)BB * HH * QP * HD;    //   917,504 B
  float* Kbuf = (float*)(wsb + 2u * 917504u);       // 134,217,728 B
  float* Vbuf = Kbuf + (size_t)BB * HH * TT * HD;   // 134,217,728 B
  float* pacc = Vbuf + (size_t)BB * HH * TT * HD;   //  13,107,200 B
  float* pl   = pacc + (size_t)BB * HH * NS * QN * HD;  // 409,600 B

  hipLaunchKernelGGL(qproj_kernel, dim3(QP * BB), dim3(DD), 0, stream,
                     tgt, qpos, Wq, bq, Qhi, Qlo);
  hipLaunchKernelGGL(kv_gemm_kernel, dim3(4096), dim3(256), 0, stream,
                     text, Wk, bk, Wv, bv, Kbuf, Vbuf);
  hipLaunchKernelGGL(prep_kernel, dim3(4096), dim3(256), 0, stream,
                     Kbuf, Vbuf);
  hipLaunchKernelGGL(attn_kernel, dim3(BB * HH * NS), dim3(256), 0, stream,
                     (const ushort*)Kbuf ? Qhi : Qhi, Qlo,
                     (const ushort*)Kbuf, (const ushort*)Vbuf,
                     oov, log_scale, pacc, pl);
  hipLaunchKernelGGL(out_kernel, dim3(QN * BB), dim3(DD), 0, stream,
                     pacc, pl, Wo, bo, tgt, ln_g, ln_b, out);
}

// Round 5
// 1384.501 us; speedup vs baseline: 1.9245x; 1.1207x over previous
//
#include <hip/hip_runtime.h>
#include <hip/hip_bf16.h>

// Problem constants
#define QN 100
#define QP 112            // padded Q rows (7 x 16)
#define BB 16
#define DD 256
#define TT 8192
#define DC 768
#define HH 8
#define HD 32
#define SL16 16           // attention T slices (512 each)
#define NPART 32          // partial slices per bh (16 sl x 2 waves)

typedef short bf16x4 __attribute__((ext_vector_type(4)));
typedef short bf16x8 __attribute__((ext_vector_type(8)));
typedef float f32x4 __attribute__((ext_vector_type(4)));
typedef _Float16 half4 __attribute__((ext_vector_type(4)));

// ---------------------------------------------------------------------------
// Kernel 1: q = (tgt+query_pos)@Wq^T + bq, head-split, l2norm, bf16 hi/lo
// planes [bh][112][32] (rows 100..111 zero). Grid 112*16 blocks x 256.
// ---------------------------------------------------------------------------
__global__ __launch_bounds__(256) void qproj_kernel(
    const float* __restrict__ tgt, const float* __restrict__ qpos,
    const float* __restrict__ Wq, const float* __restrict__ bq,
    ushort* __restrict__ Qhi, ushort* __restrict__ Qlo) {
  int bid = blockIdx.x;           // q*16 + b
  int q = bid >> 4, b = bid & 15;
  int e = threadIdx.x;            // 0..255
  int h = e >> 5, d = e & 31;
  size_t widx = ((size_t)(b * HH + h) * QP + q) * HD + d;
  if (q >= QN) { Qhi[widx] = 0; Qlo[widx] = 0; return; }
  __shared__ float arow[DD];
  size_t off = ((size_t)q * BB + b) * DD + e;
  arow[e] = tgt[off] + qpos[off];
  __syncthreads();
  const float4* w4 = (const float4*)(Wq + (size_t)e * DD);
  const float4* a4 = (const float4*)arow;
  float acc = bq[e];
#pragma unroll 8
  for (int i = 0; i < DD / 4; ++i) {
    float4 wv = w4[i], av = a4[i];
    acc += wv.x * av.x + wv.y * av.y + wv.z * av.z + wv.w * av.w;
  }
  float ss = acc * acc;
#pragma unroll
  for (int o = 16; o; o >>= 1) ss += __shfl_xor(ss, o, 64);
  float qn = acc * (1.0f / fmaxf(sqrtf(ss), 1e-6f));
  uint u = __float_as_uint(qn);
  float hif = __uint_as_float(u & 0xffff0000u);
  Qhi[widx] = (ushort)(u >> 16);
  Qlo[widx] = (ushort)(__float_as_uint(qn - hif) >> 16);
}

// ---------------------------------------------------------------------------
// Kernel 2: dual GEMM K = text@Wk^T+bk, V = text@Wv^T+bv via bf16x3-split
// MFMA. BM=128,BN=128(concat 512),BK=32, 4 waves 2x2, 4x4 16x16x32 frags.
// Ping-pong register prefetch (raA/raB) issued a FULL k-step early so the
// ~900cy uncoalesced global latency hides under convert+MFMA.
// ---------------------------------------------------------------------------
#define KV_CONVERT(RAF)                                                       \
  {                                                                           \
    const float* raf = (const float*)(RAF);                                   \
    _Pragma("unroll") for (int g = 0; g < 4; ++g) {                           \
      uint hiw[4], low[4];                                                    \
      _Pragma("unroll") for (int p2 = 0; p2 < 4; ++p2) {                      \
        float f0 = raf[8 * g + 2 * p2], f1 = raf[8 * g + 2 * p2 + 1];         \
        uint b0 = __float_as_uint(f0), b1 = __float_as_uint(f1);              \
        float h0 = __uint_as_float(b0 & 0xffff0000u);                         \
        float h1 = __uint_as_float(b1 & 0xffff0000u);                         \
        hiw[p2] = (b0 >> 16) | (b1 & 0xffff0000u);                            \
        low[p2] = (__float_as_uint(f0 - h0) >> 16) |                          \
                  (__float_as_uint(f1 - h1) & 0xffff0000u);                   \
      }                                                                       \
      *(uint4*)&dhi[g][r][0] = make_uint4(hiw[0], hiw[1], hiw[2], hiw[3]);    \
      *(uint4*)&dlo[g][r][0] = make_uint4(low[0], low[1], low[2], low[3]);    \
    }                                                                         \
  }

#define KV_MFMA()                                                             \
  {                                                                           \
    bf16x8 bhf[4], blf[4];                                                    \
    _Pragma("unroll") for (int ni = 0; ni < 4; ++ni) {                        \
      int row = wn * 64 + ni * 16 + fr;                                       \
      bhf[ni] = *(const bf16x8*)&Bhi[kg][row][0];                             \
      blf[ni] = *(const bf16x8*)&Blo[kg][row][0];                             \
    }                                                                         \
    _Pragma("unroll") for (int mi = 0; mi < 4; ++mi) {                        \
      int row = wm * 64 + mi * 16 + fr;                                       \
      bf16x8 ah = *(const bf16x8*)&Ahi[kg][row][0];                           \
      bf16x8 al = *(const bf16x8*)&Alo[kg][row][0];                           \
      _Pragma("unroll") for (int ni = 0; ni < 4; ++ni) {                      \
        acc[mi][ni] = __builtin_amdgcn_mfma_f32_16x16x32_bf16(                \
            ah, bhf[ni], acc[mi][ni], 0, 0, 0);                               \
        acc[mi][ni] = __builtin_amdgcn_mfma_f32_16x16x32_bf16(                \
            ah, blf[ni], acc[mi][ni], 0, 0, 0);                               \
        acc[mi][ni] = __builtin_amdgcn_mfma_f32_16x16x32_bf16(                \
            al, bhf[ni], acc[mi][ni], 0, 0, 0);                               \
      }                                                                       \
    }                                                                         \
  }

__global__ __launch_bounds__(256) void kv_gemm_kernel(
    const float* __restrict__ text,
    const float* __restrict__ Wk, const float* __restrict__ bk,
    const float* __restrict__ Wv, const float* __restrict__ bv,
    float* __restrict__ Kout, float* __restrict__ Vout) {
  __shared__ short Ahi[4][129][8];
  __shared__ short Alo[4][129][8];
  __shared__ short Bhi[4][129][8];
  __shared__ short Blo[4][129][8];

  int bid = blockIdx.x;                       // 0..4095
  int w = (bid & 7) * 512 + (bid >> 3);       // XCD-contiguous chunks
  int mt = w >> 2, nt = w & 3;
  int m0 = mt * 128, n0 = nt * 128;
  int tid = threadIdx.x;

  const float* Wbase = (n0 < 256) ? Wk : Wv;
  const float* bias_vec = (n0 < 256) ? bk : bv;
  float* dst = (n0 < 256) ? Kout : Vout;
  int ncol0 = n0 & 255;

  int r = tid & 127;
  bool isA = tid < 128;
  const float* src = isA ? (text + (size_t)(m0 + r) * DC)
                         : (Wbase + (size_t)(ncol0 + r) * DC);
  short (*dhi)[129][8] = isA ? Ahi : Bhi;
  short (*dlo)[129][8] = isA ? Alo : Blo;

  int lane = tid & 63, wid = tid >> 6;
  int wm = wid >> 1, wn = wid & 1;
  int kg = lane >> 4, fr = lane & 15;

  f32x4 acc[4][4];
#pragma unroll
  for (int i = 0; i < 4; ++i)
#pragma unroll
    for (int j = 0; j < 4; ++j) acc[i][j] = (f32x4){0.f, 0.f, 0.f, 0.f};

  float4 raA[8], raB[8];
#pragma unroll
  for (int c = 0; c < 8; ++c) raA[c] = *(const float4*)(src + c * 4);

  for (int ks = 0; ks < 24; ks += 2) {
    {  // prefetch chunk ks+1 (covered by convert+MFMA of chunk ks)
      const float* s2 = src + (ks + 1) * 32;
#pragma unroll
      for (int c = 0; c < 8; ++c) raB[c] = *(const float4*)(s2 + c * 4);
    }
    KV_CONVERT(raA);
    __syncthreads();
    KV_MFMA();
    __syncthreads();
    if (ks + 2 < 24) {  // prefetch chunk ks+2
      const float* s3 = src + (ks + 2) * 32;
#pragma unroll
      for (int c = 0; c < 8; ++c) raA[c] = *(const float4*)(s3 + c * 4);
    }
    KV_CONVERT(raB);
    __syncthreads();
    KV_MFMA();
    __syncthreads();
  }

#pragma unroll
  for (int ni = 0; ni < 4; ++ni) {
    int col = n0 + wn * 64 + ni * 16 + fr;
    int e = col & 255;
    int h = e >> 5, d = e & 31;
    float bias = bias_vec[e];
#pragma unroll
    for (int mi = 0; mi < 4; ++mi) {
      f32x4 c = acc[mi][ni];
      int mbase = m0 + wm * 64 + mi * 16 + kg * 4;
#pragma unroll
      for (int j = 0; j < 4; ++j) {
        int m = mbase + j;
        int b = m >> 13, t = m & 8191;
        dst[(((size_t)(b * HH + h)) * TT + t) * HD + d] = c[j] + bias;
      }
    }
  }
}

// ---------------------------------------------------------------------------
// Kernel 2.5: prep — convert K/V fp32 -> bf16 hi/lo planes IN PLACE,
// chunk-local (chunk = 256 t rows). K: l2norm folded, [2][256][32] shorts.
// V: transposed to [2][32][256] shorts. Grid 4096 x 256.
// ---------------------------------------------------------------------------
__global__ __launch_bounds__(256) void prep_kernel(float* __restrict__ Kbuf,
                                                   float* __restrict__ Vbuf) {
  __shared__ float vl[32][257];   // [d][t] padded
  int c = blockIdx.x;
  int tid = threadIdx.x;
  float* Kc = Kbuf + (size_t)c * 8192;
  float* Vc = Vbuf + (size_t)c * 8192;

  float kr[32];
#pragma unroll
  for (int i = 0; i < 8; ++i)
    *(float4*)&kr[i * 4] = *(const float4*)(Kc + (size_t)tid * 32 + i * 4);
#pragma unroll
  for (int i = 0; i < 8; ++i) {
    float4 v = *(const float4*)(Vc + (size_t)tid * 32 + i * 4);
    vl[i * 4 + 0][tid] = v.x;
    vl[i * 4 + 1][tid] = v.y;
    vl[i * 4 + 2][tid] = v.z;
    vl[i * 4 + 3][tid] = v.w;
  }
  __syncthreads();

  float ss = 0.f;
#pragma unroll
  for (int i = 0; i < 32; ++i) ss += kr[i] * kr[i];
  float rk = 1.0f / fmaxf(sqrtf(ss), 1e-6f);
  ushort* Kh = (ushort*)Kc;       // [2][256][32] shorts
  uint hiw[16], low[16];
#pragma unroll
  for (int p = 0; p < 16; ++p) {
    float f0 = kr[2 * p] * rk, f1 = kr[2 * p + 1] * rk;
    uint b0 = __float_as_uint(f0), b1 = __float_as_uint(f1);
    float h0 = __uint_as_float(b0 & 0xffff0000u);
    float h1 = __uint_as_float(b1 & 0xffff0000u);
    hiw[p] = (b0 >> 16) | (b1 & 0xffff0000u);
    low[p] = (__float_as_uint(f0 - h0) >> 16) |
             (__float_as_uint(f1 - h1) & 0xffff0000u);
  }
#pragma unroll
  for (int i = 0; i < 4; ++i) {
    *(uint4*)(Kh + (size_t)tid * 32 + i * 8) =
        make_uint4(hiw[4 * i], hiw[4 * i + 1], hiw[4 * i + 2], hiw[4 * i + 3]);
    *(uint4*)(Kh + 8192 + (size_t)tid * 32 + i * 8) =
        make_uint4(low[4 * i], low[4 * i + 1], low[4 * i + 2], low[4 * i + 3]);
  }

  int d = tid & 31, c8 = tid >> 5;
  float vv[32];
#pragma unroll
  for (int t = 0; t < 32; ++t) vv[t] = vl[d][c8 * 32 + t];
  ushort* Vh = (ushort*)Vc;       // [2][32][256] shorts
#pragma unroll
  for (int p = 0; p < 16; ++p) {
    float f0 = vv[2 * p], f1 = vv[2 * p + 1];
    uint b0 = __float_as_uint(f0), b1 = __float_as_uint(f1);
    float h0 = __uint_as_float(b0 & 0xffff0000u);
    float h1 = __uint_as_float(b1 & 0xffff0000u);
    hiw[p] = (b0 >> 16) | (b1 & 0xffff0000u);
    low[p] = (__float_as_uint(f0 - h0) >> 16) |
             (__float_as_uint(f1 - h1) & 0xffff0000u);
  }
#pragma unroll
  for (int i = 0; i < 4; ++i) {
    *(uint4*)(Vh + (size_t)d * 256 + c8 * 32 + i * 8) =
        make_uint4(hiw[4 * i], hiw[4 * i + 1], hiw[4 * i + 2], hiw[4 * i + 3]);
    *(uint4*)(Vh + 8192 + (size_t)d * 256 + c8 * 32 + i * 8) =
        make_uint4(low[4 * i], low[4 * i + 1], low[4 * i + 2], low[4 * i + 3]);
  }
}

// ---------------------------------------------------------------------------
// Kernel 2.6: oov transpose  [b][q][t] fp32 -> [b][t][128] fp16
// (q padded to 128 per t-row; rows 100..111 zeroed, 112..127 unread).
// Grid 16*128 blocks (b, 64-t chunk) x 256 threads.
// ---------------------------------------------------------------------------
__global__ __launch_bounds__(256) void oovt_kernel(
    const float* __restrict__ oov, ushort* __restrict__ oovT) {
  __shared__ ushort tile[64][116];   // [t'][q], stride 232B (8B aligned)
  int bidx = blockIdx.x;
  int b = bidx >> 7, tc = (bidx & 127) * 64;
  int tid = threadIdx.x;
#pragma unroll
  for (int rr = 0; rr < 25; ++rr) {          // 100 q x 64 t
    int idx = rr * 256 + tid;
    int q = idx >> 6, tt = idx & 63;
    float v = oov[((size_t)b * QN + q) * TT + tc + tt];
    tile[tt][q] = __builtin_bit_cast(ushort, (_Float16)v);
  }
#pragma unroll
  for (int rr = 0; rr < 3; ++rr) {           // zero pad q 100..111
    int idx = rr * 256 + tid;
    tile[idx & 63][100 + (idx >> 6)] = 0;
  }
  __syncthreads();
#pragma unroll
  for (int rr = 0; rr < 7; ++rr) {           // 64 t-rows x 28 8B-chunks
    int idx = rr * 256 + tid;
    int tt = idx / 28, jj = idx - tt * 28;
    int q0 = jj * 4;
    *(uint2*)(oovT + (((size_t)b * TT + tc + tt) << 7) + q0) =
        *(const uint2*)&tile[tt][q0];
  }
}

// ---------------------------------------------------------------------------
// Kernel 3: MFMA attention partials. Grid = bh(128) x 16 slices, 128 thr
// (2 independent waves, barrier-free). Each wave: 32-t window per 64-t step,
// 8 steps over its 512-t slice; writes its OWN partial (32 per bh).
// QK^T 3-term hi/lo; P truncated to bf16 (l sums the truncated values so
// normalization is exactly consistent); PV 2-term (Phi*Vhi + Phi*Vlo).
// ---------------------------------------------------------------------------
__global__ __launch_bounds__(128, 3) void attn_kernel(
    const ushort* __restrict__ Qhi, const ushort* __restrict__ Qlo,
    const ushort* __restrict__ Kpl, const ushort* __restrict__ Vpl,
    const ushort* __restrict__ oovT, const float* __restrict__ log_scale,
    float* __restrict__ pacc, float* __restrict__ pl) {
  __shared__ short Pbuf[2][QP][36];   // per-wave P tile, 16.1 KB
  int bid = blockIdx.x;
  int sl = bid & 15, bh = bid >> 4;
  int b = bh >> 3, h = bh & 7;
  int tid = threadIdx.x, lane = tid & 63, w = tid >> 6;
  int fr = lane & 15, kg = lane >> 4;

  float scale = fminf(__expf(log_scale[0]), 100.0f);
  float alpha = (float)h * (1.0f / 7.0f);
  float cs = scale * (1.0f - alpha);

  f32x4 oacc[7][2];
#pragma unroll
  for (int qt = 0; qt < 7; ++qt)
#pragma unroll
    for (int dt = 0; dt < 2; ++dt) oacc[qt][dt] = (f32x4){0.f, 0.f, 0.f, 0.f};
  float lsum[7][4];
#pragma unroll
  for (int qt = 0; qt < 7; ++qt)
#pragma unroll
    for (int j = 0; j < 4; ++j) lsum[qt][j] = 0.f;

  short* Ph = &Pbuf[w][0][0];
  const size_t qbase = (size_t)bh * QP * HD;

  for (int s = 0; s < 8; ++s) {
    int t0 = sl * 512 + s * 64 + w * 32;
    int c = bh * 32 + (t0 >> 8);
    int ttb = t0 & 255;
    const ushort* Kc = Kpl + (size_t)c * 16384;
    const ushort* Vc = Vpl + (size_t)c * 16384;

    bf16x8 kh[2], kl[2];
#pragma unroll
    for (int tt = 0; tt < 2; ++tt) {
      int off = (ttb + tt * 16 + fr) * HD + kg * 8;
      kh[tt] = *(const bf16x8*)(Kc + off);
      kl[tt] = *(const bf16x8*)(Kc + 8192 + off);
    }
    const ushort* ovb = oovT + (((size_t)b * TT + t0) << 7);

    // ---- QK^T + exp + truncate-split into LDS ----
#pragma unroll
    for (int qt = 0; qt < 7; ++qt) {
      size_t qa = qbase + (size_t)(qt * 16 + fr) * HD + kg * 8;
      bf16x8 qh = *(const bf16x8*)(Qhi + qa);
      bf16x8 ql = *(const bf16x8*)(Qlo + qa);
#pragma unroll
      for (int tt = 0; tt < 2; ++tt) {
        f32x4 sacc = (f32x4){0.f, 0.f, 0.f, 0.f};
        sacc = __builtin_amdgcn_mfma_f32_16x16x32_bf16(qh, kh[tt], sacc, 0, 0, 0);
        sacc = __builtin_amdgcn_mfma_f32_16x16x32_bf16(ql, kh[tt], sacc, 0, 0, 0);
        sacc = __builtin_amdgcn_mfma_f32_16x16x32_bf16(qh, kl[tt], sacc, 0, 0, 0);
        half4 hv = *(const half4*)(ovb + (size_t)(tt * 16 + fr) * 128 + qt * 16 + kg * 4);
#pragma unroll
        for (int j = 0; j < 4; ++j) {
          float S = __expf(sacc[j] * cs + (float)hv[j] * alpha);
          uint u = __float_as_uint(S) & 0xffff0000u;
          lsum[qt][j] += __uint_as_float(u);   // sum truncated values
          Ph[(qt * 16 + kg * 4 + j) * 36 + tt * 16 + fr] = (short)(u >> 16);
        }
      }
    }

    // ---- PV: 2-term (P_hi x V_hi + P_hi x V_lo) ----
    bf16x8 vh[2], vlo[2];
#pragma unroll
    for (int dt = 0; dt < 2; ++dt) {
      int off = (dt * 16 + fr) * 256 + ttb + kg * 8;
      vh[dt] = *(const bf16x8*)(Vc + off);
      vlo[dt] = *(const bf16x8*)(Vc + 8192 + off);
    }
#pragma unroll
    for (int qt = 0; qt < 7; ++qt) {
      int qrow = qt * 16 + fr;
      bf16x4 p0 = *(const bf16x4*)&Ph[qrow * 36 + kg * 8];
      bf16x4 p1 = *(const bf16x4*)&Ph[qrow * 36 + kg * 8 + 4];
      bf16x8 pv8 = __builtin_shufflevector(p0, p1, 0, 1, 2, 3, 4, 5, 6, 7);
#pragma unroll
      for (int dt = 0; dt < 2; ++dt) {
        oacc[qt][dt] = __builtin_amdgcn_mfma_f32_16x16x32_bf16(pv8, vh[dt], oacc[qt][dt], 0, 0, 0);
        oacc[qt][dt] = __builtin_amdgcn_mfma_f32_16x16x32_bf16(pv8, vlo[dt], oacc[qt][dt], 0, 0, 0);
      }
    }
  }

  // ---- reduce l over the 16 fr lanes; write per-wave partials ----
#pragma unroll
  for (int qt = 0; qt < 7; ++qt)
#pragma unroll
    for (int j = 0; j < 4; ++j) {
      float v = lsum[qt][j];
      v += __shfl_xor(v, 1, 64);
      v += __shfl_xor(v, 2, 64);
      v += __shfl_xor(v, 4, 64);
      v += __shfl_xor(v, 8, 64);
      lsum[qt][j] = v;
    }
  int ps = bh * NPART + sl * 2 + w;
  size_t pb = (size_t)ps * QN;
#pragma unroll
  for (int qt = 0; qt < 7; ++qt)
#pragma unroll
    for (int dt = 0; dt < 2; ++dt)
#pragma unroll
      for (int j = 0; j < 4; ++j) {
        int q = qt * 16 + kg * 4 + j;
        if (q < QN) pacc[(pb + q) * HD + dt * 16 + fr] = oacc[qt][dt][j];
      }
  if (fr == 0) {
#pragma unroll
    for (int qt = 0; qt < 7; ++qt)
#pragma unroll
      for (int j = 0; j < 4; ++j) {
        int q = qt * 16 + kg * 4 + j;
        if (q < QN) pl[pb + q] = lsum[qt][j];
      }
  }
}

// ---------------------------------------------------------------------------
// Kernel 4: combine 32 partials -> attn row; out = row@Wo^T + bo; res+LN.
// ---------------------------------------------------------------------------
__global__ __launch_bounds__(256) void out_kernel(
    const float* __restrict__ part_acc, const float* __restrict__ part_l,
    const float* __restrict__ Wo, const float* __restrict__ bo,
    const float* __restrict__ tgt, const float* __restrict__ ln_g,
    const float* __restrict__ ln_b, float* __restrict__ out) {
  int bid = blockIdx.x;           // q*B + b
  int q = bid >> 4, b = bid & 15;
  int e = threadIdx.x;
  int h = e >> 5, d = e & 31;
  __shared__ float row[DD];
  __shared__ float r1[4], r2[4];

  size_t base = ((size_t)(b * HH + h)) * NPART * QN + q;
  float a = 0.0f, lt = 0.0f;
#pragma unroll 8
  for (int s = 0; s < NPART; ++s) {
    a += part_acc[(base + (size_t)s * QN) * HD + d];
    lt += part_l[base + (size_t)s * QN];
  }
  row[e] = a / lt;
  __syncthreads();

  const float4* w4 = (const float4*)(Wo + (size_t)e * DD);
  const float4* r4 = (const float4*)row;
  float o = bo[e];
#pragma unroll 8
  for (int i = 0; i < DD / 4; ++i) {
    float4 wv = w4[i], rv = r4[i];
    o += wv.x * rv.x + wv.y * rv.y + wv.z * rv.z + wv.w * rv.w;
  }
  float x = tgt[((size_t)q * BB + b) * DD + e] + o;

  float s1 = x, s2 = x * x;
#pragma unroll
  for (int off = 32; off; off >>= 1) {
    s1 += __shfl_xor(s1, off, 64);
    s2 += __shfl_xor(s2, off, 64);
  }
  int wid = e >> 6, lane = e & 63;
  if (lane == 0) { r1[wid] = s1; r2[wid] = s2; }
  __syncthreads();
  float T1 = r1[0] + r1[1] + r1[2] + r1[3];
  float T2 = r2[0] + r2[1] + r2[2] + r2[3];
  float mu = T1 * (1.0f / DD);
  float var = T2 * (1.0f / DD) - mu * mu;
  out[((size_t)q * BB + b) * DD + e] =
      (x - mu) * rsqrtf(var + 1e-5f) * ln_g[e] + ln_b[e];
}

// ---------------------------------------------------------------------------
extern "C" void kernel_launch(void* const* d_in, const int* in_sizes, int n_in,
                              void* d_out, int out_size, void* d_ws, size_t ws_size,
                              hipStream_t stream) {
  (void)in_sizes; (void)n_in; (void)out_size; (void)ws_size;
  const float* tgt  = (const float*)d_in[0];
  const float* text = (const float*)d_in[1];
  const float* qpos = (const float*)d_in[2];
  const float* oov  = (const float*)d_in[3];
  const float* Wq = (const float*)d_in[4];
  const float* bq = (const float*)d_in[5];
  const float* Wk = (const float*)d_in[6];
  const float* bk = (const float*)d_in[7];
  const float* Wv = (const float*)d_in[8];
  const float* bv = (const float*)d_in[9];
  const float* Wo = (const float*)d_in[10];
  const float* bo = (const float*)d_in[11];
  const float* ln_g = (const float*)d_in[12];
  const float* ln_b = (const float*)d_in[13];
  const float* log_scale = (const float*)d_in[14];
  float* out = (float*)d_out;

  // workspace layout (~358.6 MB)
  char* wsb = (char*)d_ws;
  ushort* Qhi = (ushort*)wsb;                          //     917,504 B
  ushort* Qlo = Qhi + (size_t)BB * HH * QP * HD;       //     917,504 B
  float* Kbuf = (float*)(wsb + 2u * 917504u);          // 134,217,728 B
  float* Vbuf = Kbuf + (size_t)BB * HH * TT * HD;      // 134,217,728 B
  ushort* oovT = (ushort*)(Vbuf + (size_t)BB * HH * TT * HD); // 33,554,432 B
  float* pacc = (float*)((char*)oovT + (size_t)BB * TT * 128 * 2); // 52,428,800 B
  float* pl   = pacc + (size_t)BB * HH * NPART * QN * HD;         //  1,638,400 B

  hipLaunchKernelGGL(qproj_kernel, dim3(QP * BB), dim3(DD), 0, stream,
                     tgt, qpos, Wq, bq, Qhi, Qlo);
  hipLaunchKernelGGL(kv_gemm_kernel, dim3(4096), dim3(256), 0, stream,
                     text, Wk, bk, Wv, bv, Kbuf, Vbuf);
  hipLaunchKernelGGL(prep_kernel, dim3(4096), dim3(256), 0, stream,
                     Kbuf, Vbuf);
  hipLaunchKernelGGL(oovt_kernel, dim3(BB * 128), dim3(256), 0, stream,
                     oov, oovT);
  hipLaunchKernelGGL(attn_kernel, dim3(BB * HH * SL16), dim3(128), 0, stream,
                     Qhi, Qlo, (const ushort*)Kbuf, (const ushort*)Vbuf,
                     oovT, log_scale, pacc, pl);
  hipLaunchKernelGGL(out_kernel, dim3(QN * BB), dim3(DD), 0, stream,
                     pacc, pl, Wo, bo, tgt, ln_g, ln_b, out);
}

// Round 8
// 1332.915 us; speedup vs baseline: 1.9990x; 1.0387x over previous
//
#include <hip/hip_runtime.h>
#include <hip/hip_bf16.h>

// Problem constants
#define QN 100
#define QP 112            // padded Q rows (7 x 16)
#define BB 16
#define DD 256
#define TT 8192
#define DC 768
#define HH 8
#define HD 32
#define SL16 16           // attention T slices (512 each)
#define NPART 32          // partial slices per bh (16 sl x 2 waves)

typedef short bf16x4 __attribute__((ext_vector_type(4)));
typedef short bf16x8 __attribute__((ext_vector_type(8)));
typedef float f32x4 __attribute__((ext_vector_type(4)));
typedef _Float16 half4 __attribute__((ext_vector_type(4)));

// ---------------------------------------------------------------------------
// Kernel 1: q = (tgt+query_pos)@Wq^T + bq, head-split, l2norm, bf16 hi/lo
// planes [bh][112][32] (rows 100..111 zero). Grid 112*16 blocks x 256.
// ---------------------------------------------------------------------------
__global__ __launch_bounds__(256) void qproj_kernel(
    const float* __restrict__ tgt, const float* __restrict__ qpos,
    const float* __restrict__ Wq, const float* __restrict__ bq,
    ushort* __restrict__ Qhi, ushort* __restrict__ Qlo) {
  int bid = blockIdx.x;           // q*16 + b
  int q = bid >> 4, b = bid & 15;
  int e = threadIdx.x;            // 0..255
  int h = e >> 5, d = e & 31;
  size_t widx = ((size_t)(b * HH + h) * QP + q) * HD + d;
  if (q >= QN) { Qhi[widx] = 0; Qlo[widx] = 0; return; }
  __shared__ float arow[DD];
  size_t off = ((size_t)q * BB + b) * DD + e;
  arow[e] = tgt[off] + qpos[off];
  __syncthreads();
  const float4* w4 = (const float4*)(Wq + (size_t)e * DD);
  const float4* a4 = (const float4*)arow;
  float acc = bq[e];
#pragma unroll 8
  for (int i = 0; i < DD / 4; ++i) {
    float4 wv = w4[i], av = a4[i];
    acc += wv.x * av.x + wv.y * av.y + wv.z * av.z + wv.w * av.w;
  }
  float ss = acc * acc;
#pragma unroll
  for (int o = 16; o; o >>= 1) ss += __shfl_xor(ss, o, 64);
  float qn = acc * (1.0f / fmaxf(sqrtf(ss), 1e-6f));
  uint u = __float_as_uint(qn);
  float hif = __uint_as_float(u & 0xffff0000u);
  Qhi[widx] = (ushort)(u >> 16);
  Qlo[widx] = (ushort)(__float_as_uint(qn - hif) >> 16);
}

// ---------------------------------------------------------------------------
// Kernel 2: dual GEMM K = text@Wk^T+bk, V = text@Wv^T+bv via bf16x3-split
// MFMA. BM=128,BN=128(concat 512),BK=32, 4 waves 2x2, 4x4 16x16x32 frags.
// Ping-pong register prefetch (raA/raB) issued a FULL k-step early so the
// ~900cy uncoalesced global latency hides under convert+MFMA. (unchanged)
// ---------------------------------------------------------------------------
#define KV_CONVERT(RAF)                                                       \
  {                                                                           \
    const float* raf = (const float*)(RAF);                                   \
    _Pragma("unroll") for (int g = 0; g < 4; ++g) {                           \
      uint hiw[4], low[4];                                                    \
      _Pragma("unroll") for (int p2 = 0; p2 < 4; ++p2) {                      \
        float f0 = raf[8 * g + 2 * p2], f1 = raf[8 * g + 2 * p2 + 1];         \
        uint b0 = __float_as_uint(f0), b1 = __float_as_uint(f1);              \
        float h0 = __uint_as_float(b0 & 0xffff0000u);                         \
        float h1 = __uint_as_float(b1 & 0xffff0000u);                         \
        hiw[p2] = (b0 >> 16) | (b1 & 0xffff0000u);                            \
        low[p2] = (__float_as_uint(f0 - h0) >> 16) |                          \
                  (__float_as_uint(f1 - h1) & 0xffff0000u);                   \
      }                                                                       \
      *(uint4*)&dhi[g][r][0] = make_uint4(hiw[0], hiw[1], hiw[2], hiw[3]);    \
      *(uint4*)&dlo[g][r][0] = make_uint4(low[0], low[1], low[2], low[3]);    \
    }                                                                         \
  }

#define KV_MFMA()                                                             \
  {                                                                           \
    bf16x8 bhf[4], blf[4];                                                    \
    _Pragma("unroll") for (int ni = 0; ni < 4; ++ni) {                        \
      int row = wn * 64 + ni * 16 + fr;                                       \
      bhf[ni] = *(const bf16x8*)&Bhi[kg][row][0];                             \
      blf[ni] = *(const bf16x8*)&Blo[kg][row][0];                             \
    }                                                                         \
    _Pragma("unroll") for (int mi = 0; mi < 4; ++mi) {                        \
      int row = wm * 64 + mi * 16 + fr;                                       \
      bf16x8 ah = *(const bf16x8*)&Ahi[kg][row][0];                           \
      bf16x8 al = *(const bf16x8*)&Alo[kg][row][0];                           \
      _Pragma("unroll") for (int ni = 0; ni < 4; ++ni) {                      \
        acc[mi][ni] = __builtin_amdgcn_mfma_f32_16x16x32_bf16(                \
            ah, bhf[ni], acc[mi][ni], 0, 0, 0);                               \
        acc[mi][ni] = __builtin_amdgcn_mfma_f32_16x16x32_bf16(                \
            ah, blf[ni], acc[mi][ni], 0, 0, 0);                               \
        acc[mi][ni] = __builtin_amdgcn_mfma_f32_16x16x32_bf16(                \
            al, bhf[ni], acc[mi][ni], 0, 0, 0);                               \
      }                                                                       \
    }                                                                         \
  }

__global__ __launch_bounds__(256) void kv_gemm_kernel(
    const float* __restrict__ text,
    const float* __restrict__ Wk, const float* __restrict__ bk,
    const float* __restrict__ Wv, const float* __restrict__ bv,
    float* __restrict__ Kout, float* __restrict__ Vout) {
  __shared__ short Ahi[4][129][8];
  __shared__ short Alo[4][129][8];
  __shared__ short Bhi[4][129][8];
  __shared__ short Blo[4][129][8];

  int bid = blockIdx.x;                       // 0..4095
  int w = (bid & 7) * 512 + (bid >> 3);       // XCD-contiguous chunks
  int mt = w >> 2, nt = w & 3;
  int m0 = mt * 128, n0 = nt * 128;
  int tid = threadIdx.x;

  const float* Wbase = (n0 < 256) ? Wk : Wv;
  const float* bias_vec = (n0 < 256) ? bk : bv;
  float* dst = (n0 < 256) ? Kout : Vout;
  int ncol0 = n0 & 255;

  int r = tid & 127;
  bool isA = tid < 128;
  const float* src = isA ? (text + (size_t)(m0 + r) * DC)
                         : (Wbase + (size_t)(ncol0 + r) * DC);
  short (*dhi)[129][8] = isA ? Ahi : Bhi;
  short (*dlo)[129][8] = isA ? Alo : Blo;

  int lane = tid & 63, wid = tid >> 6;
  int wm = wid >> 1, wn = wid & 1;
  int kg = lane >> 4, fr = lane & 15;

  f32x4 acc[4][4];
#pragma unroll
  for (int i = 0; i < 4; ++i)
#pragma unroll
    for (int j = 0; j < 4; ++j) acc[i][j] = (f32x4){0.f, 0.f, 0.f, 0.f};

  float4 raA[8], raB[8];
#pragma unroll
  for (int c = 0; c < 8; ++c) raA[c] = *(const float4*)(src + c * 4);

  for (int ks = 0; ks < 24; ks += 2) {
    {  // prefetch chunk ks+1 (covered by convert+MFMA of chunk ks)
      const float* s2 = src + (ks + 1) * 32;
#pragma unroll
      for (int c = 0; c < 8; ++c) raB[c] = *(const float4*)(s2 + c * 4);
    }
    KV_CONVERT(raA);
    __syncthreads();
    KV_MFMA();
    __syncthreads();
    if (ks + 2 < 24) {  // prefetch chunk ks+2
      const float* s3 = src + (ks + 2) * 32;
#pragma unroll
      for (int c = 0; c < 8; ++c) raA[c] = *(const float4*)(s3 + c * 4);
    }
    KV_CONVERT(raB);
    __syncthreads();
    KV_MFMA();
    __syncthreads();
  }

#pragma unroll
  for (int ni = 0; ni < 4; ++ni) {
    int col = n0 + wn * 64 + ni * 16 + fr;
    int e = col & 255;
    int h = e >> 5, d = e & 31;
    float bias = bias_vec[e];
#pragma unroll
    for (int mi = 0; mi < 4; ++mi) {
      f32x4 c = acc[mi][ni];
      int mbase = m0 + wm * 64 + mi * 16 + kg * 4;
#pragma unroll
      for (int j = 0; j < 4; ++j) {
        int m = mbase + j;
        int b = m >> 13, t = m & 8191;
        dst[(((size_t)(b * HH + h)) * TT + t) * HD + d] = c[j] + bias;
      }
    }
  }
}

// ---------------------------------------------------------------------------
// Kernel 2.5: prep — convert K/V fp32 -> bf16 hi/lo planes IN PLACE,
// chunk-local (chunk = 256 t rows). K: l2norm folded, [2][256][32] shorts.
// V: transposed to [2][32][256] shorts. Grid 4096 x 256. (unchanged)
// ---------------------------------------------------------------------------
__global__ __launch_bounds__(256) void prep_kernel(float* __restrict__ Kbuf,
                                                   float* __restrict__ Vbuf) {
  __shared__ float vl[32][257];   // [d][t] padded
  int c = blockIdx.x;
  int tid = threadIdx.x;
  float* Kc = Kbuf + (size_t)c * 8192;
  float* Vc = Vbuf + (size_t)c * 8192;

  float kr[32];
#pragma unroll
  for (int i = 0; i < 8; ++i)
    *(float4*)&kr[i * 4] = *(const float4*)(Kc + (size_t)tid * 32 + i * 4);
#pragma unroll
  for (int i = 0; i < 8; ++i) {
    float4 v = *(const float4*)(Vc + (size_t)tid * 32 + i * 4);
    vl[i * 4 + 0][tid] = v.x;
    vl[i * 4 + 1][tid] = v.y;
    vl[i * 4 + 2][tid] = v.z;
    vl[i * 4 + 3][tid] = v.w;
  }
  __syncthreads();

  float ss = 0.f;
#pragma unroll
  for (int i = 0; i < 32; ++i) ss += kr[i] * kr[i];
  float rk = 1.0f / fmaxf(sqrtf(ss), 1e-6f);
  ushort* Kh = (ushort*)Kc;       // [2][256][32] shorts
  uint hiw[16], low[16];
#pragma unroll
  for (int p = 0; p < 16; ++p) {
    float f0 = kr[2 * p] * rk, f1 = kr[2 * p + 1] * rk;
    uint b0 = __float_as_uint(f0), b1 = __float_as_uint(f1);
    float h0 = __uint_as_float(b0 & 0xffff0000u);
    float h1 = __uint_as_float(b1 & 0xffff0000u);
    hiw[p] = (b0 >> 16) | (b1 & 0xffff0000u);
    low[p] = (__float_as_uint(f0 - h0) >> 16) |
             (__float_as_uint(f1 - h1) & 0xffff0000u);
  }
#pragma unroll
  for (int i = 0; i < 4; ++i) {
    *(uint4*)(Kh + (size_t)tid * 32 + i * 8) =
        make_uint4(hiw[4 * i], hiw[4 * i + 1], hiw[4 * i + 2], hiw[4 * i + 3]);
    *(uint4*)(Kh + 8192 + (size_t)tid * 32 + i * 8) =
        make_uint4(low[4 * i], low[4 * i + 1], low[4 * i + 2], low[4 * i + 3]);
  }

  int d = tid & 31, c8 = tid >> 5;
  float vv[32];
#pragma unroll
  for (int t = 0; t < 32; ++t) vv[t] = vl[d][c8 * 32 + t];
  ushort* Vh = (ushort*)Vc;       // [2][32][256] shorts
#pragma unroll
  for (int p = 0; p < 16; ++p) {
    float f0 = vv[2 * p], f1 = vv[2 * p + 1];
    uint b0 = __float_as_uint(f0), b1 = __float_as_uint(f1);
    float h0 = __uint_as_float(b0 & 0xffff0000u);
    float h1 = __uint_as_float(b1 & 0xffff0000u);
    hiw[p] = (b0 >> 16) | (b1 & 0xffff0000u);
    low[p] = (__float_as_uint(f0 - h0) >> 16) |
             (__float_as_uint(f1 - h1) & 0xffff0000u);
  }
#pragma unroll
  for (int i = 0; i < 4; ++i) {
    *(uint4*)(Vh + (size_t)d * 256 + c8 * 32 + i * 8) =
        make_uint4(hiw[4 * i], hiw[4 * i + 1], hiw[4 * i + 2], hiw[4 * i + 3]);
    *(uint4*)(Vh + 8192 + (size_t)d * 256 + c8 * 32 + i * 8) =
        make_uint4(low[4 * i], low[4 * i + 1], low[4 * i + 2], low[4 * i + 3]);
  }
}

// ---------------------------------------------------------------------------
// Kernel 2.6: oov transpose  [b][q][t] fp32 -> [b][t][128] fp16  (unchanged)
// ---------------------------------------------------------------------------
__global__ __launch_bounds__(256) void oovt_kernel(
    const float* __restrict__ oov, ushort* __restrict__ oovT) {
  __shared__ ushort tile[64][116];   // [t'][q], stride 232B (8B aligned)
  int bidx = blockIdx.x;
  int b = bidx >> 7, tc = (bidx & 127) * 64;
  int tid = threadIdx.x;
#pragma unroll
  for (int rr = 0; rr < 25; ++rr) {          // 100 q x 64 t
    int idx = rr * 256 + tid;
    int q = idx >> 6, tt = idx & 63;
    float v = oov[((size_t)b * QN + q) * TT + tc + tt];
    tile[tt][q] = __builtin_bit_cast(ushort, (_Float16)v);
  }
#pragma unroll
  for (int rr = 0; rr < 3; ++rr) {           // zero pad q 100..111
    int idx = rr * 256 + tid;
    tile[idx & 63][100 + (idx >> 6)] = 0;
  }
  __syncthreads();
#pragma unroll
  for (int rr = 0; rr < 7; ++rr) {           // 64 t-rows x 28 8B-chunks
    int idx = rr * 256 + tid;
    int tt = idx / 28, jj = idx - tt * 28;
    int q0 = jj * 4;
    *(uint2*)(oovT + (((size_t)b * TT + tc + tt) << 7) + q0) =
        *(const uint2*)&tile[tt][q0];
  }
}

// ---------------------------------------------------------------------------
// Kernel 3: MFMA attention partials. Grid = bh(128) x 16 slices, 128 thr
// (2 independent waves, barrier-free). Each wave: 32-t window per 64-t step.
// v2: NO launch_bounds min-waves (r5's (128,3) forced VGPR<=170 -> likely
// accumulator spill = the ~676us anomaly). Explicit pipeline: K preloaded,
// V issued at step top (lands under QK+exp), next-step K issued between QK
// and PV (lands under exp+PV). exp2f with 1/ln2 folded into constants.
// ---------------------------------------------------------------------------
__global__ __launch_bounds__(128) void attn_kernel(
    const ushort* __restrict__ Qhi, const ushort* __restrict__ Qlo,
    const ushort* __restrict__ Kpl, const ushort* __restrict__ Vpl,
    const ushort* __restrict__ oovT, const float* __restrict__ log_scale,
    float* __restrict__ pacc, float* __restrict__ pl) {
  __shared__ short Pbuf[2][QP][36];   // per-wave P tile, 16.1 KB
  int bid = blockIdx.x;
  int sl = bid & 15, bh = bid >> 4;
  int b = bh >> 3, h = bh & 7;
  int tid = threadIdx.x, lane = tid & 63, w = tid >> 6;
  int fr = lane & 15, kg = lane >> 4;

  const float LOG2E = 1.4426950408889634f;
  float scale = fminf(__expf(log_scale[0]), 100.0f);
  float alpha = (float)h * (1.0f / 7.0f);
  float cs2 = scale * (1.0f - alpha) * LOG2E;
  float al2 = alpha * LOG2E;

  f32x4 oacc[7][2];
#pragma unroll
  for (int qt = 0; qt < 7; ++qt)
#pragma unroll
    for (int dt = 0; dt < 2; ++dt) oacc[qt][dt] = (f32x4){0.f, 0.f, 0.f, 0.f};
  float lsum[7][4];
#pragma unroll
  for (int qt = 0; qt < 7; ++qt)
#pragma unroll
    for (int j = 0; j < 4; ++j) lsum[qt][j] = 0.f;

  short* Ph = &Pbuf[w][0][0];
  const size_t qbase = (size_t)bh * QP * HD;

  // preload K fragments for step 0
  bf16x8 khA[2], klA[2];
  {
    int t0 = sl * 512 + w * 32;
    int c = bh * 32 + (t0 >> 8);
    int ttb = t0 & 255;
    const ushort* Kc = Kpl + (size_t)c * 16384;
#pragma unroll
    for (int tt = 0; tt < 2; ++tt) {
      int off = (ttb + tt * 16 + fr) * HD + kg * 8;
      khA[tt] = *(const bf16x8*)(Kc + off);
      klA[tt] = *(const bf16x8*)(Kc + 8192 + off);
    }
  }

  for (int s = 0; s < 8; ++s) {
    int t0 = sl * 512 + s * 64 + w * 32;
    int c = bh * 32 + (t0 >> 8);
    int ttb = t0 & 255;
    const ushort* Vc = Vpl + (size_t)c * 16384;

    // issue V loads now; consumed after exp (~1300cy later)
    bf16x8 vh[2], vlo[2];
#pragma unroll
    for (int dt = 0; dt < 2; ++dt) {
      int off = (dt * 16 + fr) * 256 + ttb + kg * 8;
      vh[dt] = *(const bf16x8*)(Vc + off);
      vlo[dt] = *(const bf16x8*)(Vc + 8192 + off);
    }
    const ushort* ovb = oovT + (((size_t)b * TT + t0) << 7);

    // ---- QK^T + exp2 + truncate-split into LDS ----
#pragma unroll
    for (int qt = 0; qt < 7; ++qt) {
      size_t qa = qbase + (size_t)(qt * 16 + fr) * HD + kg * 8;
      bf16x8 qh = *(const bf16x8*)(Qhi + qa);
      bf16x8 ql = *(const bf16x8*)(Qlo + qa);
#pragma unroll
      for (int tt = 0; tt < 2; ++tt) {
        f32x4 sacc = (f32x4){0.f, 0.f, 0.f, 0.f};
        sacc = __builtin_amdgcn_mfma_f32_16x16x32_bf16(qh, khA[tt], sacc, 0, 0, 0);
        sacc = __builtin_amdgcn_mfma_f32_16x16x32_bf16(ql, khA[tt], sacc, 0, 0, 0);
        sacc = __builtin_amdgcn_mfma_f32_16x16x32_bf16(qh, klA[tt], sacc, 0, 0, 0);
        half4 hv = *(const half4*)(ovb + (size_t)(tt * 16 + fr) * 128 + qt * 16 + kg * 4);
#pragma unroll
        for (int j = 0; j < 4; ++j) {
          float S = exp2f(sacc[j] * cs2 + (float)hv[j] * al2);
          uint u = __float_as_uint(S) & 0xffff0000u;
          lsum[qt][j] += __uint_as_float(u);   // sum truncated values
          Ph[(qt * 16 + kg * 4 + j) * 36 + tt * 16 + fr] = (short)(u >> 16);
        }
      }
    }

    // prefetch next-step K (lands under exp tail + PV MFMAs)
    bf16x8 khB[2], klB[2];
    {
      int sn = (s + 1) & 7;                 // wraps on last iter (harmless)
      int t0n = sl * 512 + sn * 64 + w * 32;
      int cn = bh * 32 + (t0n >> 8);
      int ttbn = t0n & 255;
      const ushort* Kn = Kpl + (size_t)cn * 16384;
#pragma unroll
      for (int tt = 0; tt < 2; ++tt) {
        int off = (ttbn + tt * 16 + fr) * HD + kg * 8;
        khB[tt] = *(const bf16x8*)(Kn + off);
        klB[tt] = *(const bf16x8*)(Kn + 8192 + off);
      }
    }

    // ---- PV: 2-term (P_hi x V_hi + P_hi x V_lo) ----
#pragma unroll
    for (int qt = 0; qt < 7; ++qt) {
      int qrow = qt * 16 + fr;
      bf16x4 p0 = *(const bf16x4*)&Ph[qrow * 36 + kg * 8];
      bf16x4 p1 = *(const bf16x4*)&Ph[qrow * 36 + kg * 8 + 4];
      bf16x8 pv8 = __builtin_shufflevector(p0, p1, 0, 1, 2, 3, 4, 5, 6, 7);
#pragma unroll
      for (int dt = 0; dt < 2; ++dt) {
        oacc[qt][dt] = __builtin_amdgcn_mfma_f32_16x16x32_bf16(pv8, vh[dt], oacc[qt][dt], 0, 0, 0);
        oacc[qt][dt] = __builtin_amdgcn_mfma_f32_16x16x32_bf16(pv8, vlo[dt], oacc[qt][dt], 0, 0, 0);
      }
    }

    khA[0] = khB[0]; khA[1] = khB[1];
    klA[0] = klB[0]; klA[1] = klB[1];
  }

  // ---- reduce l over the 16 fr lanes; write per-wave partials ----
#pragma unroll
  for (int qt = 0; qt < 7; ++qt)
#pragma unroll
    for (int j = 0; j < 4; ++j) {
      float v = lsum[qt][j];
      v += __shfl_xor(v, 1, 64);
      v += __shfl_xor(v, 2, 64);
      v += __shfl_xor(v, 4, 64);
      v += __shfl_xor(v, 8, 64);
      lsum[qt][j] = v;
    }
  int ps = bh * NPART + sl * 2 + w;
  size_t pb = (size_t)ps * QN;
#pragma unroll
  for (int qt = 0; qt < 7; ++qt)
#pragma unroll
    for (int dt = 0; dt < 2; ++dt)
#pragma unroll
      for (int j = 0; j < 4; ++j) {
        int q = qt * 16 + kg * 4 + j;
        if (q < QN) pacc[(pb + q) * HD + dt * 16 + fr] = oacc[qt][dt][j];
      }
  if (fr == 0) {
#pragma unroll
    for (int qt = 0; qt < 7; ++qt)
#pragma unroll
      for (int j = 0; j < 4; ++j) {
        int q = qt * 16 + kg * 4 + j;
        if (q < QN) pl[pb + q] = lsum[qt][j];
      }
  }
}

// ---------------------------------------------------------------------------
// Kernel 4: combine 32 partials -> attn row; out = row@Wo^T + bo; res+LN.
// ---------------------------------------------------------------------------
__global__ __launch_bounds__(256) void out_kernel(
    const float* __restrict__ part_acc, const float* __restrict__ part_l,
    const float* __restrict__ Wo, const float* __restrict__ bo,
    const float* __restrict__ tgt, const float* __restrict__ ln_g,
    const float* __restrict__ ln_b, float* __restrict__ out) {
  int bid = blockIdx.x;           // q*B + b
  int q = bid >> 4, b = bid & 15;
  int e = threadIdx.x;
  int h = e >> 5, d = e & 31;
  __shared__ float row[DD];
  __shared__ float r1[4], r2[4];

  size_t base = ((size_t)(b * HH + h)) * NPART * QN + q;
  float a = 0.0f, lt = 0.0f;
#pragma unroll 8
  for (int s = 0; s < NPART; ++s) {
    a += part_acc[(base + (size_t)s * QN) * HD + d];
    lt += part_l[base + (size_t)s * QN];
  }
  row[e] = a / lt;
  __syncthreads();

  const float4* w4 = (const float4*)(Wo + (size_t)e * DD);
  const float4* r4 = (const float4*)row;
  float o = bo[e];
#pragma unroll 8
  for (int i = 0; i < DD / 4; ++i) {
    float4 wv = w4[i], rv = r4[i];
    o += wv.x * rv.x + wv.y * rv.y + wv.z * rv.z + wv.w * rv.w;
  }
  float x = tgt[((size_t)q * BB + b) * DD + e] + o;

  float s1 = x, s2 = x * x;
#pragma unroll
  for (int off = 32; off; off >>= 1) {
    s1 += __shfl_xor(s1, off, 64);
    s2 += __shfl_xor(s2, off, 64);
  }
  int wid = e >> 6, lane = e & 63;
  if (lane == 0) { r1[wid] = s1; r2[wid] = s2; }
  __syncthreads();
  float T1 = r1[0] + r1[1] + r1[2] + r1[3];
  float T2 = r2[0] + r2[1] + r2[2] + r2[3];
  float mu = T1 * (1.0f / DD);
  float var = T2 * (1.0f / DD) - mu * mu;
  out[((size_t)q * BB + b) * DD + e] =
      (x - mu) * rsqrtf(var + 1e-5f) * ln_g[e] + ln_b[e];
}

// ---------------------------------------------------------------------------
extern "C" void kernel_launch(void* const* d_in, const int* in_sizes, int n_in,
                              void* d_out, int out_size, void* d_ws, size_t ws_size,
                              hipStream_t stream) {
  (void)in_sizes; (void)n_in; (void)out_size; (void)ws_size;
  const float* tgt  = (const float*)d_in[0];
  const float* text = (const float*)d_in[1];
  const float* qpos = (const float*)d_in[2];
  const float* oov  = (const float*)d_in[3];
  const float* Wq = (const float*)d_in[4];
  const float* bq = (const float*)d_in[5];
  const float* Wk = (const float*)d_in[6];
  const float* bk = (const float*)d_in[7];
  const float* Wv = (const float*)d_in[8];
  const float* bv = (const float*)d_in[9];
  const float* Wo = (const float*)d_in[10];
  const float* bo = (const float*)d_in[11];
  const float* ln_g = (const float*)d_in[12];
  const float* ln_b = (const float*)d_in[13];
  const float* log_scale = (const float*)d_in[14];
  float* out = (float*)d_out;

  // workspace layout (~358.6 MB)
  char* wsb = (char*)d_ws;
  ushort* Qhi = (ushort*)wsb;                          //     917,504 B
  ushort* Qlo = Qhi + (size_t)BB * HH * QP * HD;       //     917,504 B
  float* Kbuf = (float*)(wsb + 2u * 917504u);          // 134,217,728 B
  float* Vbuf = Kbuf + (size_t)BB * HH * TT * HD;      // 134,217,728 B
  ushort* oovT = (ushort*)(Vbuf + (size_t)BB * HH * TT * HD); // 33,554,432 B
  float* pacc = (float*)((char*)oovT + (size_t)BB * TT * 128 * 2); // 52,428,800 B
  float* pl   = pacc + (size_t)BB * HH * NPART * QN * HD;         //  1,638,400 B

  hipLaunchKernelGGL(qproj_kernel, dim3(QP * BB), dim3(DD), 0, stream,
                     tgt, qpos, Wq, bq, Qhi, Qlo);
  hipLaunchKernelGGL(kv_gemm_kernel, dim3(4096), dim3(256), 0, stream,
                     text, Wk, bk, Wv, bv, Kbuf, Vbuf);
  hipLaunchKernelGGL(prep_kernel, dim3(4096), dim3(256), 0, stream,
                     Kbuf, Vbuf);
  hipLaunchKernelGGL(oovt_kernel, dim3(BB * 128), dim3(256), 0, stream,
                     oov, oovT);
  hipLaunchKernelGGL(attn_kernel, dim3(BB * HH * SL16), dim3(128), 0, stream,
                     Qhi, Qlo, (const ushort*)Kbuf, (const ushort*)Vbuf,
                     oovT, log_scale, pacc, pl);
  hipLaunchKernelGGL(out_kernel, dim3(QN * BB), dim3(DD), 0, stream,
                     pacc, pl, Wo, bo, tgt, ln_g, ln_b, out);
}